// Round 1
// baseline (309.054 us; speedup 1.0000x reference)
//
#include <hip/hip_runtime.h>

#define BSZ 32
#define DIM 64
#define SEQ 2048
#define KE  1024

// output offsets in floats
#define O0 0ull            // quantized_st [BS][D][S]
#define O1 4194304ull      // loss (scalar)
#define O2 4194305ull      // one_hot [BS][K][S]
#define O3 71303169ull     // indices [BS][S] (as float)
#define O4 71368705ull     // distance [BS][K][S]
#define O5 138477569ull    // unquantized [BS*S][D]
#define O6 142671873ull    // embeddings.T [K][D]

// Kernel 0: transpose E -> out6 and aligned ws copy; b2[k] = ||e_k||^2; zero loss.
__global__ __launch_bounds__(256) void vq_prep(const float* __restrict__ E,
                                               float* __restrict__ out,
                                               float* __restrict__ et_ws,
                                               float* __restrict__ b2_ws) {
    __shared__ float T[64][65];
    const int tid  = threadIdx.x;
    const int lane = tid & 63;
    const int sub  = tid >> 6;
    const int k0   = blockIdx.x * 64;
    // load E[d][k0+lane], coalesced over k
    for (int dd = 0; dd < 16; ++dd) {
        int d = dd * 4 + sub;
        T[d][lane] = E[(size_t)d * KE + k0 + lane];
    }
    __syncthreads();
    // write rows of E^T: out6[(k0+kl)*64 + d], coalesced over d
    for (int ii = 0; ii < 16; ++ii) {
        int kl = ii * 4 + sub;
        float v = T[lane][kl];               // stride-65 read: conflict-free
        out[O6 + (size_t)(k0 + kl) * 64 + lane] = v;
        et_ws[(size_t)(k0 + kl) * 64 + lane]    = v;
    }
    if (tid < 64) {
        float s = 0.f;
        #pragma unroll
        for (int d = 0; d < 64; ++d) {
            float v = T[d][tid];
            s = fmaf(v, v, s);
        }
        b2_ws[k0 + tid] = s;
    }
    if (blockIdx.x == 0 && tid == 0) out[O1] = 0.f;
}

// Kernel 1: distances, argmin, distance/one_hot/indices/quantized/loss.
// grid = 32 batches * 32 s-tiles; block = 256 (4 waves); lane = s within tile.
__global__ __launch_bounds__(256, 4) void vq_main(const float* __restrict__ x,
                                                  const float* __restrict__ et,
                                                  const float* __restrict__ b2,
                                                  float* __restrict__ out) {
    __shared__ float4 et4[2048];   // 128 k x 64 d fp32 = 32 KB
    __shared__ float  b2c[128];
    __shared__ float  mD[4][64];
    __shared__ int    mK[4][64];
    __shared__ int    idxs[64];
    float* etl = (float*)et4;

    const int tid  = threadIdx.x;
    const int lane = tid & 63;
    const int wv   = tid >> 6;
    const int b    = blockIdx.x >> 5;
    const int s0   = (blockIdx.x & 31) << 6;
    const int s    = s0 + lane;

    // x row for this lane's s: 64 regs, static indexing only
    const float* xp = x + ((size_t)b << 17) + s;   // D*S = 2^17
    float xr[64];
    #pragma unroll
    for (int d = 0; d < 64; ++d) xr[d] = xp[(size_t)d << 11];   // S = 2^11
    float a2 = 0.f;
    #pragma unroll
    for (int d = 0; d < 64; ++d) a2 = fmaf(xr[d], xr[d], a2);

    float bestD = 3.4e38f;
    int   bestK = 0;
    float* outD = out + O4 + ((size_t)b << 21) + s;   // K*S = 2^21

    for (int c = 0; c < 8; ++c) {
        const int kc = c << 7;   // chunk of 128 k
        __syncthreads();
        // stage 32 KB of E^T chunk (aligned ws copy)
        const float4* src = (const float4*)(et + ((size_t)kc << 6));
        #pragma unroll
        for (int i = 0; i < 8; ++i) et4[i * 256 + tid] = src[i * 256 + tid];
        if (tid < 128) b2c[tid] = b2[kc + tid];
        __syncthreads();
        // wave wv handles k in [kc + wv*32, +32): ascending within wave
        for (int kk = 0; kk < 32; ++kk) {
            const int kl = (wv << 5) + kk;
            const int k  = kc + kl;
            const float4* ep = (const float4*)(etl + (kl << 6));  // uniform addr -> broadcast
            float d0 = 0.f, d1 = 0.f, d2 = 0.f, d3 = 0.f;
            #pragma unroll
            for (int g = 0; g < 16; ++g) {
                float4 e = ep[g];
                d0 = fmaf(xr[4*g+0], e.x, d0);
                d1 = fmaf(xr[4*g+1], e.y, d1);
                d2 = fmaf(xr[4*g+2], e.z, d2);
                d3 = fmaf(xr[4*g+3], e.w, d3);
            }
            float dot  = (d0 + d1) + (d2 + d3);
            float dist = fmaf(-2.f, dot, a2 + b2c[kl]);
            outD[(size_t)k << 11] = dist;                 // coalesced over s
            if (dist < bestD) { bestD = dist; bestK = k; }  // first-occurrence within wave
        }
    }
    mD[wv][lane] = bestD;
    mK[wv][lane] = bestK;
    __syncthreads();
    if (tid < 64) {
        float bD = mD[0][tid]; int bK = mK[0][tid];
        #pragma unroll
        for (int w = 1; w < 4; ++w) {
            float dw = mD[w][tid]; int kw = mK[w][tid];
            if (dw < bD || (dw == bD && kw < bK)) { bD = dw; bK = kw; }  // lexicographic: global first-min
        }
        idxs[tid] = bK;
        out[O3 + (size_t)b * SEQ + s0 + tid] = (float)bK;
    }
    __syncthreads();
    const int myidx = idxs[lane];

    // one_hot sweep: 4 waves cover 4 consecutive k rows per iter, coalesced over s
    float* outH = out + O2 + ((size_t)b << 21) + s0 + lane;
    for (int i = 0; i < 256; ++i) {
        int k = (i << 2) + wv;
        outH[(size_t)k << 11] = (k == myidx) ? 1.f : 0.f;
    }

    // quantized_st + loss: wave 0 only (has x in regs, lane = s)
    if (wv == 0) {
        const float* q = et + ((size_t)myidx << 6);
        float* outQ = out + O0 + ((size_t)b << 17) + s;
        float lsum = 0.f;
        #pragma unroll
        for (int d = 0; d < 64; ++d) {
            float qv = q[d];
            outQ[(size_t)d << 11] = qv;     // coalesced over s
            float df = qv - xr[d];
            lsum = fmaf(df, df, lsum);
        }
        #pragma unroll
        for (int m = 32; m >= 1; m >>= 1) lsum += __shfl_xor(lsum, m, 64);
        if (lane == 0) atomicAdd(out + O1, lsum * (2.f / 4194304.f));
    }
}

// Kernel 2: unquantized = x transposed to [BS*S][D]
__global__ __launch_bounds__(256) void vq_unq(const float* __restrict__ x,
                                              float* __restrict__ out) {
    __shared__ float T[64][65];
    const int tid  = threadIdx.x;
    const int lane = tid & 63;
    const int sub  = tid >> 6;
    const int b    = blockIdx.x >> 5;
    const int s0   = (blockIdx.x & 31) << 6;
    const float* xp = x + ((size_t)b << 17) + s0;
    for (int dd = 0; dd < 16; ++dd) {
        int d = dd * 4 + sub;
        T[d][lane] = xp[((size_t)d << 11) + lane];   // coalesced over s
    }
    __syncthreads();
    float* op = out + O5 + (((size_t)b << 11) + s0) * 64;
    for (int ii = 0; ii < 16; ++ii) {
        int sl = ii * 4 + sub;
        op[(size_t)sl * 64 + lane] = T[lane][sl];    // coalesced over d; stride-65 LDS read
    }
}

extern "C" void kernel_launch(void* const* d_in, const int* in_sizes, int n_in,
                              void* d_out, int out_size, void* d_ws, size_t ws_size,
                              hipStream_t stream) {
    const float* x = (const float*)d_in[0];
    const float* E = (const float*)d_in[1];
    float* out   = (float*)d_out;
    float* et_ws = (float*)d_ws;          // 65536 floats: E^T, 16B-aligned
    float* b2_ws = et_ws + 65536;         // 1024 floats
    vq_prep<<<16, 256, 0, stream>>>(E, out, et_ws, b2_ws);
    vq_main<<<1024, 256, 0, stream>>>(x, et_ws, b2_ws, out);
    vq_unq<<<1024, 256, 0, stream>>>(x, out);
}

// Round 2
// 276.622 us; speedup vs baseline: 1.1172x; 1.1172x over previous
//
#include <hip/hip_runtime.h>

typedef float f32x16 __attribute__((ext_vector_type(16)));

#define BSZ 32
#define DIM 64
#define SEQ 2048
#define KE  1024

// output offsets in floats
#define O0 0ull            // quantized_st [BS][D][S]
#define O1 4194304ull      // loss (scalar)
#define O2 4194305ull      // one_hot [BS][K][S]
#define O3 71303169ull     // indices [BS][S] (as float)
#define O4 71368705ull     // distance [BS][K][S]
#define O5 138477569ull    // unquantized [BS*S][D]
#define O6 142671873ull    // embeddings.T [K][D]

// Kernel 0: transpose E -> out6 and aligned ws copy; b2[k] = ||e_k||^2; zero loss.
__global__ __launch_bounds__(256) void vq_prep(const float* __restrict__ E,
                                               float* __restrict__ out,
                                               float* __restrict__ et_ws,
                                               float* __restrict__ b2_ws) {
    __shared__ float T[64][65];
    const int tid  = threadIdx.x;
    const int lane = tid & 63;
    const int sub  = tid >> 6;
    const int k0   = blockIdx.x * 64;
    for (int dd = 0; dd < 16; ++dd) {
        int d = dd * 4 + sub;
        T[d][lane] = E[(size_t)d * KE + k0 + lane];
    }
    __syncthreads();
    for (int ii = 0; ii < 16; ++ii) {
        int kl = ii * 4 + sub;
        float v = T[lane][kl];
        out[O6 + (size_t)(k0 + kl) * 64 + lane] = v;
        et_ws[(size_t)(k0 + kl) * 64 + lane]    = v;
    }
    if (tid < 64) {
        float s = 0.f;
        #pragma unroll
        for (int d = 0; d < 64; ++d) {
            float v = T[d][tid];
            s = fmaf(v, v, s);
        }
        b2_ws[k0 + tid] = s;
    }
    if (blockIdx.x == 0 && tid == 0) out[O1] = 0.f;
}

// Kernel 1: distances via SGPR-resident e_k (scalar loads), argmin, outputs.
// grid = 32 batches * 32 s-tiles; block = 256 (4 waves); lane = s; wave = k-range.
__global__ __launch_bounds__(256, 4) void vq_main(const float* __restrict__ x,
                                                  const float* __restrict__ et,
                                                  const float* __restrict__ b2,
                                                  float* __restrict__ out) {
    __shared__ float mD[4][64];
    __shared__ int   mK[4][64];
    __shared__ int   idxs[64];

    const int tid  = threadIdx.x;
    const int lane = tid & 63;
    const int wv   = __builtin_amdgcn_readfirstlane(tid >> 6);
    const int b    = blockIdx.x >> 5;
    const int s0   = (blockIdx.x & 31) << 6;
    const int s    = s0 + lane;

    // x row for this lane's s: 64 regs, static indexing only
    const float* xp = x + ((size_t)b << 17) + s;   // D*S = 2^17
    float xr[64];
    #pragma unroll
    for (int d = 0; d < 64; ++d) xr[d] = xp[(size_t)d << 11];   // S = 2^11
    float a2 = 0.f;
    #pragma unroll
    for (int d = 0; d < 64; ++d) a2 = fmaf(xr[d], xr[d], a2);

    float bestD = 3.4e38f;
    int   bestK = wv << 8;
    float* outD = out + O4 + ((size_t)b << 21) + s;   // K*S = 2^21

    // wave wv owns k in [wv*256, wv*256+256), visited ascending (first-min ok)
    const int kbase = wv << 8;
    #pragma unroll 1
    for (int kk = 0; kk < 256; ++kk) {
        const int k = kbase + kk;
        const float* ep = et + ((size_t)k << 6);   // wave-uniform address
        f32x16 e0, e1, e2, e3;
        float  bb;
        asm volatile("s_load_dwordx16 %0, %1, 0x0"  : "=s"(e0) : "s"(ep));
        asm volatile("s_load_dwordx16 %0, %1, 0x40" : "=s"(e1) : "s"(ep));
        asm volatile("s_load_dwordx16 %0, %1, 0x80" : "=s"(e2) : "s"(ep));
        asm volatile("s_load_dwordx16 %0, %1, 0xc0" : "=s"(e3) : "s"(ep));
        asm volatile("s_load_dword %0, %1, 0x0"     : "=s"(bb) : "s"(b2 + k));
        // fmacs depend on these outputs -> cannot be hoisted above the wait
        asm volatile("s_waitcnt lgkmcnt(0)"
                     : "+s"(e0), "+s"(e1), "+s"(e2), "+s"(e3), "+s"(bb));
        float d0 = 0.f, d1 = 0.f, d2 = 0.f, d3 = 0.f;
        #pragma unroll
        for (int j = 0; j < 16; ++j) {
            d0 = fmaf(xr[j],      e0[j], d0);   // v_fmac v, s, v
            d1 = fmaf(xr[16 + j], e1[j], d1);
            d2 = fmaf(xr[32 + j], e2[j], d2);
            d3 = fmaf(xr[48 + j], e3[j], d3);
        }
        float dist = fmaf(-2.f, (d0 + d1) + (d2 + d3), a2 + bb);
        outD[(size_t)k << 11] = dist;                 // coalesced over s
        if (dist < bestD) { bestD = dist; bestK = k; }  // first-occurrence within wave
    }

    mD[wv][lane] = bestD;
    mK[wv][lane] = bestK;
    __syncthreads();
    if (tid < 64) {
        float bD = mD[0][tid]; int bK = mK[0][tid];
        #pragma unroll
        for (int w = 1; w < 4; ++w) {
            float dw = mD[w][tid]; int kw = mK[w][tid];
            if (dw < bD || (dw == bD && kw < bK)) { bD = dw; bK = kw; }  // global first-min
        }
        idxs[tid] = bK;
        out[O3 + (size_t)b * SEQ + s0 + tid] = (float)bK;
    }
    __syncthreads();
    const int myidx = idxs[lane];

    // one_hot sweep: 4 waves cover 4 consecutive k rows per iter, coalesced over s
    float* outH = out + O2 + ((size_t)b << 21) + s0 + lane;
    for (int i = 0; i < 256; ++i) {
        int k = (i << 2) + wv;
        outH[(size_t)k << 11] = (k == myidx) ? 1.f : 0.f;
    }

    // quantized_st + loss: wave 0 only (has x in regs, lane = s)
    if (wv == 0) {
        const float* q = et + ((size_t)myidx << 6);
        float* outQ = out + O0 + ((size_t)b << 17) + s;
        float lsum = 0.f;
        #pragma unroll
        for (int d = 0; d < 64; ++d) {
            float qv = q[d];
            outQ[(size_t)d << 11] = qv;     // coalesced over s
            float df = qv - xr[d];
            lsum = fmaf(df, df, lsum);
        }
        #pragma unroll
        for (int m = 32; m >= 1; m >>= 1) lsum += __shfl_xor(lsum, m, 64);
        if (lane == 0) atomicAdd(out + O1, lsum * (2.f / 4194304.f));
    }
}

// Kernel 2: unquantized = x transposed to [BS*S][D]
__global__ __launch_bounds__(256) void vq_unq(const float* __restrict__ x,
                                              float* __restrict__ out) {
    __shared__ float T[64][65];
    const int tid  = threadIdx.x;
    const int lane = tid & 63;
    const int sub  = tid >> 6;
    const int b    = blockIdx.x >> 5;
    const int s0   = (blockIdx.x & 31) << 6;
    const float* xp = x + ((size_t)b << 17) + s0;
    for (int dd = 0; dd < 16; ++dd) {
        int d = dd * 4 + sub;
        T[d][lane] = xp[((size_t)d << 11) + lane];
    }
    __syncthreads();
    float* op = out + O5 + (((size_t)b << 11) + s0) * 64;
    for (int ii = 0; ii < 16; ++ii) {
        int sl = ii * 4 + sub;
        op[(size_t)sl * 64 + lane] = T[lane][sl];
    }
}

extern "C" void kernel_launch(void* const* d_in, const int* in_sizes, int n_in,
                              void* d_out, int out_size, void* d_ws, size_t ws_size,
                              hipStream_t stream) {
    const float* x = (const float*)d_in[0];
    const float* E = (const float*)d_in[1];
    float* out   = (float*)d_out;
    float* et_ws = (float*)d_ws;          // 65536 floats: E^T, 64B-aligned rows
    float* b2_ws = et_ws + 65536;         // 1024 floats
    vq_prep<<<16, 256, 0, stream>>>(E, out, et_ws, b2_ws);
    vq_main<<<1024, 256, 0, stream>>>(x, et_ws, b2_ws, out);
    vq_unq<<<1024, 256, 0, stream>>>(x, out);
}